// Round 3
// baseline (243.072 us; speedup 1.0000x reference)
//
#include <hip/hip_runtime.h>
#include <hip/hip_bf16.h>

#define NNODES 50000
#define BKT 64   // bucket capacity; deg ~ Poisson(12.5), P(>64) ~ 1e-38 (clamped)
#define LP 136   // padded bf16 LDS row (272 B = 16*17): b128-aligned, mild bank stagger
#define EPT 8    // edges per thread in bucket role (8 independent atomic chains)
#define AGG_BLOCKS 2048

typedef short bf16x8 __attribute__((ext_vector_type(8)));
typedef float f32x4 __attribute__((ext_vector_type(4)));

__device__ __forceinline__ unsigned short f2bf_rn(float f) {
    unsigned int u = __float_as_uint(f);
    return (unsigned short)((u + 0x7fffu + ((u >> 16) & 1u)) >> 16);
}
__device__ __forceinline__ float bf_lo(unsigned int u) { return __uint_as_float(u << 16); }
__device__ __forceinline__ float bf_hi(unsigned int u) { return __uint_as_float(u & 0xffff0000u); }

// ---- k_wt: blocks 0,1 transpose W->bf16 WT[c][k]; blocks 2+ zero cnt ----

__global__ __launch_bounds__(256) void k_wt(const float* __restrict__ W1,
                                            const float* __restrict__ W2,
                                            unsigned short* __restrict__ WT1,
                                            unsigned short* __restrict__ WT2,
                                            int* __restrict__ cnt, int N) {
    __shared__ float tile[128 * 129];
    int b = blockIdx.x, t = threadIdx.x;
    if (b < 2) {
        const float* W = b ? W2 : W1;
        unsigned short* WT = b ? WT2 : WT1;
        for (int idx = t; idx < 128 * 128; idx += 256)
            tile[(idx >> 7) * 129 + (idx & 127)] = W[idx];
        __syncthreads();
        for (int idx = t; idx < 128 * 128; idx += 256) {
            int c = idx >> 7, k = idx & 127;
            WT[c * 128 + k] = f2bf_rn(tile[k * 129 + c]);
        }
    } else {
        int i = (b - 2) * 256 + t;
        if (i < N) cnt[i] = 0;
    }
}

// ---- gather-accumulate with per-edge dinv (layer 1; sources NOT prescaled) ----

__device__ __forceinline__ void gather_accum(const unsigned int* __restrict__ xwb,
                                             const int* __restrict__ cnt,
                                             const unsigned short* __restrict__ bp,
                                             int degc, int lane,
                                             float& ax, float& ay) {
    float px = 0.f, py = 0.f;
    int j = 0;
    for (; j + 8 <= degc; j += 8) {
        int4 q = *(const int4*)&bp[j];  // 8 x u16 ids
        int s0 = q.x & 0xffff, s1 = (int)((unsigned)q.x >> 16);
        int s2 = q.y & 0xffff, s3 = (int)((unsigned)q.y >> 16);
        int s4 = q.z & 0xffff, s5 = (int)((unsigned)q.z >> 16);
        int s6 = q.w & 0xffff, s7 = (int)((unsigned)q.w >> 16);
        unsigned int u0 = xwb[(size_t)s0 * 64 + lane];
        unsigned int u1 = xwb[(size_t)s1 * 64 + lane];
        unsigned int u2 = xwb[(size_t)s2 * 64 + lane];
        unsigned int u3 = xwb[(size_t)s3 * 64 + lane];
        unsigned int u4 = xwb[(size_t)s4 * 64 + lane];
        unsigned int u5 = xwb[(size_t)s5 * 64 + lane];
        unsigned int u6 = xwb[(size_t)s6 * 64 + lane];
        unsigned int u7 = xwb[(size_t)s7 * 64 + lane];
        float w0 = rsqrtf((float)cnt[s0] + 1.0f), w1 = rsqrtf((float)cnt[s1] + 1.0f);
        float w2 = rsqrtf((float)cnt[s2] + 1.0f), w3 = rsqrtf((float)cnt[s3] + 1.0f);
        float w4 = rsqrtf((float)cnt[s4] + 1.0f), w5 = rsqrtf((float)cnt[s5] + 1.0f);
        float w6 = rsqrtf((float)cnt[s6] + 1.0f), w7 = rsqrtf((float)cnt[s7] + 1.0f);
        ax = fmaf(bf_lo(u0), w0, ax);  ay = fmaf(bf_hi(u0), w0, ay);
        px = fmaf(bf_lo(u1), w1, px);  py = fmaf(bf_hi(u1), w1, py);
        ax = fmaf(bf_lo(u2), w2, ax);  ay = fmaf(bf_hi(u2), w2, ay);
        px = fmaf(bf_lo(u3), w3, px);  py = fmaf(bf_hi(u3), w3, py);
        ax = fmaf(bf_lo(u4), w4, ax);  ay = fmaf(bf_hi(u4), w4, ay);
        px = fmaf(bf_lo(u5), w5, px);  py = fmaf(bf_hi(u5), w5, py);
        ax = fmaf(bf_lo(u6), w6, ax);  ay = fmaf(bf_hi(u6), w6, ay);
        px = fmaf(bf_lo(u7), w7, px);  py = fmaf(bf_hi(u7), w7, py);
    }
    if (j + 4 <= degc) {
        int2 q = *(const int2*)&bp[j];
        int s0 = q.x & 0xffff, s1 = (int)((unsigned)q.x >> 16);
        int s2 = q.y & 0xffff, s3 = (int)((unsigned)q.y >> 16);
        unsigned int u0 = xwb[(size_t)s0 * 64 + lane];
        unsigned int u1 = xwb[(size_t)s1 * 64 + lane];
        unsigned int u2 = xwb[(size_t)s2 * 64 + lane];
        unsigned int u3 = xwb[(size_t)s3 * 64 + lane];
        float w0 = rsqrtf((float)cnt[s0] + 1.0f), w1 = rsqrtf((float)cnt[s1] + 1.0f);
        float w2 = rsqrtf((float)cnt[s2] + 1.0f), w3 = rsqrtf((float)cnt[s3] + 1.0f);
        ax = fmaf(bf_lo(u0), w0, ax);  ay = fmaf(bf_hi(u0), w0, ay);
        px = fmaf(bf_lo(u1), w1, px);  py = fmaf(bf_hi(u1), w1, py);
        ax = fmaf(bf_lo(u2), w2, ax);  ay = fmaf(bf_hi(u2), w2, ay);
        px = fmaf(bf_lo(u3), w3, px);  py = fmaf(bf_hi(u3), w3, py);
        j += 4;
    }
    for (; j < degc; ++j) {
        int s = bp[j];
        float wv = rsqrtf((float)cnt[s] + 1.0f);
        unsigned int u = xwb[(size_t)s * 64 + lane];
        ax = fmaf(bf_lo(u), wv, ax);
        ay = fmaf(bf_hi(u), wv, ay);
    }
    ax += px;
    ay += py;
}

// ---- pure-sum gather (layer 2; sources PRESCALED by dinv at xw2 write) ----

__device__ __forceinline__ void gather_sum(const unsigned int* __restrict__ xwb,
                                           const unsigned short* __restrict__ bp,
                                           int degc, int lane,
                                           float& ax, float& ay) {
    float px = 0.f, py = 0.f;
    int j = 0;
    for (; j + 8 <= degc; j += 8) {
        int4 q = *(const int4*)&bp[j];
        int s0 = q.x & 0xffff, s1 = (int)((unsigned)q.x >> 16);
        int s2 = q.y & 0xffff, s3 = (int)((unsigned)q.y >> 16);
        int s4 = q.z & 0xffff, s5 = (int)((unsigned)q.z >> 16);
        int s6 = q.w & 0xffff, s7 = (int)((unsigned)q.w >> 16);
        unsigned int u0 = xwb[(size_t)s0 * 64 + lane];
        unsigned int u1 = xwb[(size_t)s1 * 64 + lane];
        unsigned int u2 = xwb[(size_t)s2 * 64 + lane];
        unsigned int u3 = xwb[(size_t)s3 * 64 + lane];
        unsigned int u4 = xwb[(size_t)s4 * 64 + lane];
        unsigned int u5 = xwb[(size_t)s5 * 64 + lane];
        unsigned int u6 = xwb[(size_t)s6 * 64 + lane];
        unsigned int u7 = xwb[(size_t)s7 * 64 + lane];
        ax += bf_lo(u0);  ay += bf_hi(u0);
        px += bf_lo(u1);  py += bf_hi(u1);
        ax += bf_lo(u2);  ay += bf_hi(u2);
        px += bf_lo(u3);  py += bf_hi(u3);
        ax += bf_lo(u4);  ay += bf_hi(u4);
        px += bf_lo(u5);  py += bf_hi(u5);
        ax += bf_lo(u6);  ay += bf_hi(u6);
        px += bf_lo(u7);  py += bf_hi(u7);
    }
    if (j + 4 <= degc) {
        int2 q = *(const int2*)&bp[j];
        int s0 = q.x & 0xffff, s1 = (int)((unsigned)q.x >> 16);
        int s2 = q.y & 0xffff, s3 = (int)((unsigned)q.y >> 16);
        unsigned int u0 = xwb[(size_t)s0 * 64 + lane];
        unsigned int u1 = xwb[(size_t)s1 * 64 + lane];
        unsigned int u2 = xwb[(size_t)s2 * 64 + lane];
        unsigned int u3 = xwb[(size_t)s3 * 64 + lane];
        ax += bf_lo(u0);  ay += bf_hi(u0);
        px += bf_lo(u1);  py += bf_hi(u1);
        ax += bf_lo(u2);  ay += bf_hi(u2);
        px += bf_lo(u3);  py += bf_hi(u3);
        j += 4;
    }
    for (; j < degc; ++j) {
        int s = bp[j];
        unsigned int u = xwb[(size_t)s * 64 + lane];
        ax += bf_lo(u);
        ay += bf_hi(u);
    }
    ax += px;
    ay += py;
}

// ---- merged gemm1 + bucket build, roles INTERLEAVED in dispatch order ----

__global__ __launch_bounds__(256) void k_gemmbucket(const float* __restrict__ X,
                                                    const unsigned short* __restrict__ WT,
                                                    unsigned short* __restrict__ Yb, int n,
                                                    const int* __restrict__ src,
                                                    const int* __restrict__ dst,
                                                    int* __restrict__ cnt,
                                                    unsigned short* __restrict__ bkt,
                                                    int E, int EB8) {
    __shared__ unsigned short Ep[64 * LP];  // 17.4 KB epilogue tile (gemm role)
    int t = threadIdx.x;
    int b = blockIdx.x;
    int region = EB8 * 3;
    if (b < region && (b % 3) == 0) {  // ---- bucket role ----
        int bid = b / 3;
        int e0 = bid * 256 * EPT + t * EPT;
        if (e0 + EPT <= E) {
            int4 sa = *(const int4*)&src[e0];
            int4 sb = *(const int4*)&src[e0 + 4];
            int4 da = *(const int4*)&dst[e0];
            int4 db = *(const int4*)&dst[e0 + 4];
            int p;
            p = atomicAdd(&cnt[da.x], 1); if (p < BKT) bkt[(size_t)da.x * BKT + p] = (unsigned short)sa.x;
            p = atomicAdd(&cnt[da.y], 1); if (p < BKT) bkt[(size_t)da.y * BKT + p] = (unsigned short)sa.y;
            p = atomicAdd(&cnt[da.z], 1); if (p < BKT) bkt[(size_t)da.z * BKT + p] = (unsigned short)sa.z;
            p = atomicAdd(&cnt[da.w], 1); if (p < BKT) bkt[(size_t)da.w * BKT + p] = (unsigned short)sa.w;
            p = atomicAdd(&cnt[db.x], 1); if (p < BKT) bkt[(size_t)db.x * BKT + p] = (unsigned short)sb.x;
            p = atomicAdd(&cnt[db.y], 1); if (p < BKT) bkt[(size_t)db.y * BKT + p] = (unsigned short)sb.y;
            p = atomicAdd(&cnt[db.z], 1); if (p < BKT) bkt[(size_t)db.z * BKT + p] = (unsigned short)sb.z;
            p = atomicAdd(&cnt[db.w], 1); if (p < BKT) bkt[(size_t)db.w * BKT + p] = (unsigned short)sb.w;
        } else {
#pragma unroll
            for (int k = 0; k < EPT; ++k) {
                int e = e0 + k;
                if (e < E) {
                    int s = src[e], d = dst[e];
                    int pos = atomicAdd(&cnt[d], 1);
                    if (pos < BKT) bkt[(size_t)d * BKT + pos] = (unsigned short)s;
                }
            }
        }
        return;
    }
    // ---- gemm role ----
    int gb = (b < region) ? (b - (b + 2) / 3) : (b - EB8);
    int lane = t & 63, w = t >> 6;
    int m = lane & 15, quad = lane >> 4;
    int base = gb * 64 + w * 16;
    int row = min(base + m, n - 1);  // duplicate-row tail; stores guarded

    bf16x8 a[4];
#pragma unroll
    for (int kt = 0; kt < 4; ++kt) {
        const float* pa = &X[(size_t)row * 128 + kt * 32 + quad * 8];
        float4 v0 = *(const float4*)pa;
        float4 v1 = *(const float4*)(pa + 4);
        a[kt][0] = (short)f2bf_rn(v0.x); a[kt][1] = (short)f2bf_rn(v0.y);
        a[kt][2] = (short)f2bf_rn(v0.z); a[kt][3] = (short)f2bf_rn(v0.w);
        a[kt][4] = (short)f2bf_rn(v1.x); a[kt][5] = (short)f2bf_rn(v1.y);
        a[kt][6] = (short)f2bf_rn(v1.z); a[kt][7] = (short)f2bf_rn(v1.w);
    }

    f32x4 acc[8];
#pragma unroll
    for (int i = 0; i < 8; ++i) acc[i] = f32x4{0.f, 0.f, 0.f, 0.f};
#pragma unroll
    for (int kt = 0; kt < 4; ++kt) {
        int ko = kt * 32 + quad * 8;
#pragma unroll
        for (int ct = 0; ct < 8; ++ct) {
            bf16x8 bfrag = *(const bf16x8*)&WT[(ct * 16 + m) * 128 + ko];  // L1/L2-resident
            acc[ct] = __builtin_amdgcn_mfma_f32_16x16x32_bf16(a[kt], bfrag, acc[ct], 0, 0, 0);
        }
    }

    unsigned short* ep = &Ep[w * 16 * LP];
#pragma unroll
    for (int ct = 0; ct < 8; ++ct)
#pragma unroll
        for (int r = 0; r < 4; ++r)
            ep[(quad * 4 + r) * LP + ct * 16 + m] = f2bf_rn(acc[ct][r]);
    __syncthreads();
    int rr = lane & 15, cc = lane >> 4;
    int orow = base + rr;
    if (orow < n) {
#pragma unroll
        for (int i2 = 0; i2 < 4; ++i2)
            ((uint4*)&Yb[(size_t)orow * 128])[cc * 4 + i2] =
                *(const uint4*)&ep[rr * LP + (cc * 4 + i2) * 8];
    }
}

// ---- fused agg(layer1)+gemm2: WAVE-INDEPENDENT tiles ----
// Block = 4 waves. W2 staged to LDS once (single barrier). Each wave owns 16
// nodes: gathers h-rows into its PRIVATE LDS A-tile, runs its own 16x128 MFMA,
// reuses the A-tile for the prescaled bf16 epilogue, stores coalesced. No
// cross-wave sync after staging -> gather latency of one wave overlaps other
// waves' compute; no barrier waits on slow (high-degree) waves.

__global__ __launch_bounds__(256) void k_aggemm(const unsigned int* __restrict__ xw1,
                                                const int* __restrict__ cnt,
                                                const unsigned short* __restrict__ bkt,
                                                const float* __restrict__ bias,
                                                const unsigned short* __restrict__ WT2,
                                                unsigned short* __restrict__ xw2, int n) {
    __shared__ unsigned short Wl[128 * LP];     // 34 KB staged W2
    __shared__ unsigned short At[4 * 16 * LP];  // 17 KB: 4 private wave tiles
    __shared__ float dsw[4][16];                // per-node dinv for epilogue
    int t = threadIdx.x, lane = t & 63, w = t >> 6;
    int m = lane & 15, quad = lane >> 4;

    for (int idx = t; idx < 128 * 16; idx += 256) {
        int r = idx >> 4, c8 = (idx & 15) << 3;
        *(uint4*)&Wl[r * LP + c8] = *(const uint4*)&WT2[r * 128 + c8];
    }
    float bx = bias[lane * 2], by = bias[lane * 2 + 1];
    __syncthreads();  // the only barrier

    unsigned short* Aw = &At[w * 16 * LP];
    int base = blockIdx.x * 64 + w * 16;

    // phase A: gather+activate 16 h-rows into private tile
    for (int nd = 0; nd < 16; ++nd) {
        int i = min(base + nd, n - 1);
        int deg = cnt[i];
        int degc = min(deg, BKT);
        float di = rsqrtf((float)deg + 1.0f);
        unsigned int v0 = xw1[(size_t)i * 64 + lane];
        float ax = di * bf_lo(v0), ay = di * bf_hi(v0);
        gather_accum(xw1, cnt, &bkt[(size_t)i * BKT], degc, lane, ax, ay);
        ax = fmaxf(fmaf(di, ax, bx), 0.0f);
        ay = fmaxf(fmaf(di, ay, by), 0.0f);
        ((unsigned int*)&Aw[nd * LP])[lane] =
            (unsigned)f2bf_rn(ax) | ((unsigned)f2bf_rn(ay) << 16);
        if (lane == 0) dsw[w][nd] = di;
    }

    // phase B: wave-local gemm2 (A from private tile, B from staged W2)
    bf16x8 a[4];
#pragma unroll
    for (int kt = 0; kt < 4; ++kt)
        a[kt] = *(const bf16x8*)&Aw[m * LP + kt * 32 + quad * 8];
    f32x4 acc[8];
#pragma unroll
    for (int i = 0; i < 8; ++i) acc[i] = f32x4{0.f, 0.f, 0.f, 0.f};
#pragma unroll
    for (int kt = 0; kt < 4; ++kt) {
        int ko = kt * 32 + quad * 8;
#pragma unroll
        for (int ct = 0; ct < 8; ++ct) {
            bf16x8 bfrag = *(const bf16x8*)&Wl[(ct * 16 + m) * LP + ko];
            acc[ct] = __builtin_amdgcn_mfma_f32_16x16x32_bf16(a[kt], bfrag, acc[ct], 0, 0, 0);
        }
    }

    // epilogue: prescale by dinv_row, pack bf16 into own tile, coalesced store
    float dr[4];
#pragma unroll
    for (int r = 0; r < 4; ++r) dr[r] = dsw[w][quad * 4 + r];
#pragma unroll
    for (int ct = 0; ct < 8; ++ct)
#pragma unroll
        for (int r = 0; r < 4; ++r)
            Aw[(quad * 4 + r) * LP + ct * 16 + m] = f2bf_rn(acc[ct][r] * dr[r]);
    int rr = lane & 15, cc = lane >> 4;
    int orow = base + rr;
    if (orow < n) {
#pragma unroll
        for (int i2 = 0; i2 < 4; ++i2)
            ((uint4*)&xw2[(size_t)orow * 128])[cc * 4 + i2] =
                *(const uint4*)&Aw[rr * LP + (cc * 4 + i2) * 8];
    }
}

// ---- final aggregate (layer 2): prescaled sources -> pure row sum ----

__global__ __launch_bounds__(256) void k_agg(const unsigned int* __restrict__ xwb,
                                             const int* __restrict__ cnt,
                                             const unsigned short* __restrict__ bkt,
                                             const float* __restrict__ bias,
                                             float* __restrict__ out, int n) {
    int lane = threadIdx.x & 63;
    int gw = (blockIdx.x * 256 + threadIdx.x) >> 6;
    int nw = (gridDim.x * 256) >> 6;
    float bx = bias[lane * 2], by = bias[lane * 2 + 1];
    for (int i = gw; i < n; i += nw) {
        int deg = cnt[i];
        int degc = min(deg, BKT);
        float di = rsqrtf((float)deg + 1.0f);
        unsigned int v0 = xwb[(size_t)i * 64 + lane];
        float ax = bf_lo(v0), ay = bf_hi(v0);  // self term already prescaled
        gather_sum(xwb, &bkt[(size_t)i * BKT], degc, lane, ax, ay);
        ax = fmaxf(fmaf(di, ax, bx), 0.0f);
        ay = fmaxf(fmaf(di, ay, by), 0.0f);
        ((float2*)out)[(size_t)i * 64 + lane] = make_float2(ax, ay);
    }
}

// ---------------- launch ----------------

extern "C" void kernel_launch(void* const* d_in, const int* in_sizes, int n_in,
                              void* d_out, int out_size, void* d_ws, size_t ws_size,
                              hipStream_t stream) {
    const float* x  = (const float*)d_in[0];
    const int*   ei = (const int*)d_in[1];
    const float* W1 = (const float*)d_in[2];
    const float* b1 = (const float*)d_in[3];
    const float* W2 = (const float*)d_in[4];
    const float* b2 = (const float*)d_in[5];
    float* out = (float*)d_out;

    const int N = NNODES;
    const int E = in_sizes[1] / 2;  // 625000
    const int* src = ei;
    const int* dst = ei + E;

    char* p = (char*)d_ws;
    size_t off = 0;
    auto take = [&](size_t bytes) -> void* {
        void* r = p + off;
        off = (off + bytes + 255) & ~(size_t)255;
        return r;
    };
    int* cnt = (int*)take((size_t)N * 4);
    unsigned short* bkt = (unsigned short*)take((size_t)N * BKT * 2);  // 6.4 MB u16
    unsigned short* w1t = (unsigned short*)take(128 * 128 * 2);
    unsigned short* w2t = (unsigned short*)take(128 * 128 * 2);
    unsigned short* xw1 = (unsigned short*)take((size_t)N * 128 * 2);  // bf16 x@W1
    unsigned short* xw2 = (unsigned short*)take((size_t)N * 128 * 2);  // bf16 dinv*(h@W2)

    const int NB = (N + 255) / 256;              // cnt-zero blocks
    const int EB8 = (E + 256 * EPT - 1) / (256 * EPT);  // 306 bucket blocks
    const int GB = (N + 63) / 64;                // 782 gemm blocks

    // 1: W transposes + cnt zero
    k_wt<<<2 + NB, 256, 0, stream>>>(W1, W2, w1t, w2t, cnt, N);
    // 2: interleaved bucket build + gemm1 (disjoint inputs, co-resident roles)
    k_gemmbucket<<<EB8 + GB, 256, 0, stream>>>(x, w1t, xw1, N, src, dst, cnt, bkt, E, EB8);
    // 3: fused agg(layer1)+bias+relu+gemm2 (+free dinv prescale of xw2), wave-independent
    k_aggemm<<<GB, 256, 0, stream>>>((const unsigned int*)xw1, cnt, bkt, b1, w2t, xw2, N);
    // 4: final aggregate + bias + relu (fp32 out)
    k_agg<<<AGG_BLOCKS, 256, 0, stream>>>((const unsigned int*)xw2, cnt, bkt,
                                          b2, out, N);
}

// Round 4
// 192.714 us; speedup vs baseline: 1.2613x; 1.2613x over previous
//
#include <hip/hip_runtime.h>
#include <hip/hip_bf16.h>

#define NNODES 50000
#define BKT 64   // bucket capacity; deg ~ Poisson(12.5), P(>64) ~ 1e-38 (clamped)
#define LP 136   // padded bf16 LDS row (272 B = 16*17): b128-aligned, mild bank stagger
#define EPT 8    // edges per thread in bucket role (8 independent atomic chains)
#define AGG_BLOCKS 2048

typedef short bf16x8 __attribute__((ext_vector_type(8)));
typedef float f32x4 __attribute__((ext_vector_type(4)));

__device__ __forceinline__ unsigned short f2bf_rn(float f) {
    unsigned int u = __float_as_uint(f);
    return (unsigned short)((u + 0x7fffu + ((u >> 16) & 1u)) >> 16);
}
__device__ __forceinline__ float bf_lo(unsigned int u) { return __uint_as_float(u << 16); }
__device__ __forceinline__ float bf_hi(unsigned int u) { return __uint_as_float(u & 0xffff0000u); }

// ---- k_wt: blocks 0,1 transpose W->bf16 WT[c][k]; blocks 2+ zero cnt ----

__global__ __launch_bounds__(256) void k_wt(const float* __restrict__ W1,
                                            const float* __restrict__ W2,
                                            unsigned short* __restrict__ WT1,
                                            unsigned short* __restrict__ WT2,
                                            int* __restrict__ cnt, int N) {
    __shared__ float tile[128 * 129];
    int b = blockIdx.x, t = threadIdx.x;
    if (b < 2) {
        const float* W = b ? W2 : W1;
        unsigned short* WT = b ? WT2 : WT1;
        for (int idx = t; idx < 128 * 128; idx += 256)
            tile[(idx >> 7) * 129 + (idx & 127)] = W[idx];
        __syncthreads();
        for (int idx = t; idx < 128 * 128; idx += 256) {
            int c = idx >> 7, k = idx & 127;
            WT[c * 128 + k] = f2bf_rn(tile[k * 129 + c]);
        }
    } else {
        int i = (b - 2) * 256 + t;
        if (i < N) cnt[i] = 0;
    }
}

// ---- weighted gather (layer 1): weight = dinv[s] from f32 LUT ----
// Bit-identical accumulation order to the original gather_accum (rsqrt values
// precomputed in k_dinv), minus the per-edge cnt load / cvt / rsqrt chain.

__device__ __forceinline__ void gather_wsum(const unsigned int* __restrict__ xwb,
                                            const float* __restrict__ dinv,
                                            const unsigned short* __restrict__ bp,
                                            int degc, int lane,
                                            float& ax, float& ay) {
    float px = 0.f, py = 0.f;
    int j = 0;
    for (; j + 8 <= degc; j += 8) {
        int4 q = *(const int4*)&bp[j];  // 8 x u16 ids
        int s0 = q.x & 0xffff, s1 = (int)((unsigned)q.x >> 16);
        int s2 = q.y & 0xffff, s3 = (int)((unsigned)q.y >> 16);
        int s4 = q.z & 0xffff, s5 = (int)((unsigned)q.z >> 16);
        int s6 = q.w & 0xffff, s7 = (int)((unsigned)q.w >> 16);
        unsigned int u0 = xwb[(size_t)s0 * 64 + lane];
        unsigned int u1 = xwb[(size_t)s1 * 64 + lane];
        unsigned int u2 = xwb[(size_t)s2 * 64 + lane];
        unsigned int u3 = xwb[(size_t)s3 * 64 + lane];
        unsigned int u4 = xwb[(size_t)s4 * 64 + lane];
        unsigned int u5 = xwb[(size_t)s5 * 64 + lane];
        unsigned int u6 = xwb[(size_t)s6 * 64 + lane];
        unsigned int u7 = xwb[(size_t)s7 * 64 + lane];
        float w0 = dinv[s0], w1 = dinv[s1], w2 = dinv[s2], w3 = dinv[s3];
        float w4 = dinv[s4], w5 = dinv[s5], w6 = dinv[s6], w7 = dinv[s7];
        ax = fmaf(bf_lo(u0), w0, ax);  ay = fmaf(bf_hi(u0), w0, ay);
        px = fmaf(bf_lo(u1), w1, px);  py = fmaf(bf_hi(u1), w1, py);
        ax = fmaf(bf_lo(u2), w2, ax);  ay = fmaf(bf_hi(u2), w2, ay);
        px = fmaf(bf_lo(u3), w3, px);  py = fmaf(bf_hi(u3), w3, py);
        ax = fmaf(bf_lo(u4), w4, ax);  ay = fmaf(bf_hi(u4), w4, ay);
        px = fmaf(bf_lo(u5), w5, px);  py = fmaf(bf_hi(u5), w5, py);
        ax = fmaf(bf_lo(u6), w6, ax);  ay = fmaf(bf_hi(u6), w6, ay);
        px = fmaf(bf_lo(u7), w7, px);  py = fmaf(bf_hi(u7), w7, py);
    }
    if (j + 4 <= degc) {
        int2 q = *(const int2*)&bp[j];
        int s0 = q.x & 0xffff, s1 = (int)((unsigned)q.x >> 16);
        int s2 = q.y & 0xffff, s3 = (int)((unsigned)q.y >> 16);
        unsigned int u0 = xwb[(size_t)s0 * 64 + lane];
        unsigned int u1 = xwb[(size_t)s1 * 64 + lane];
        unsigned int u2 = xwb[(size_t)s2 * 64 + lane];
        unsigned int u3 = xwb[(size_t)s3 * 64 + lane];
        float w0 = dinv[s0], w1 = dinv[s1], w2 = dinv[s2], w3 = dinv[s3];
        ax = fmaf(bf_lo(u0), w0, ax);  ay = fmaf(bf_hi(u0), w0, ay);
        px = fmaf(bf_lo(u1), w1, px);  py = fmaf(bf_hi(u1), w1, py);
        ax = fmaf(bf_lo(u2), w2, ax);  ay = fmaf(bf_hi(u2), w2, ay);
        px = fmaf(bf_lo(u3), w3, px);  py = fmaf(bf_hi(u3), w3, py);
        j += 4;
    }
    for (; j < degc; ++j) {
        int s = bp[j];
        float wv = dinv[s];
        unsigned int u = xwb[(size_t)s * 64 + lane];
        ax = fmaf(bf_lo(u), wv, ax);
        ay = fmaf(bf_hi(u), wv, ay);
    }
    ax += px;
    ay += py;
}

// ---- pure-sum gather (layer 2; sources PRESCALED by dinv at xw2 write) ----

__device__ __forceinline__ void gather_sum(const unsigned int* __restrict__ xwb,
                                           const unsigned short* __restrict__ bp,
                                           int degc, int lane,
                                           float& ax, float& ay) {
    float px = 0.f, py = 0.f;
    int j = 0;
    for (; j + 8 <= degc; j += 8) {
        int4 q = *(const int4*)&bp[j];
        int s0 = q.x & 0xffff, s1 = (int)((unsigned)q.x >> 16);
        int s2 = q.y & 0xffff, s3 = (int)((unsigned)q.y >> 16);
        int s4 = q.z & 0xffff, s5 = (int)((unsigned)q.z >> 16);
        int s6 = q.w & 0xffff, s7 = (int)((unsigned)q.w >> 16);
        unsigned int u0 = xwb[(size_t)s0 * 64 + lane];
        unsigned int u1 = xwb[(size_t)s1 * 64 + lane];
        unsigned int u2 = xwb[(size_t)s2 * 64 + lane];
        unsigned int u3 = xwb[(size_t)s3 * 64 + lane];
        unsigned int u4 = xwb[(size_t)s4 * 64 + lane];
        unsigned int u5 = xwb[(size_t)s5 * 64 + lane];
        unsigned int u6 = xwb[(size_t)s6 * 64 + lane];
        unsigned int u7 = xwb[(size_t)s7 * 64 + lane];
        ax += bf_lo(u0);  ay += bf_hi(u0);
        px += bf_lo(u1);  py += bf_hi(u1);
        ax += bf_lo(u2);  ay += bf_hi(u2);
        px += bf_lo(u3);  py += bf_hi(u3);
        ax += bf_lo(u4);  ay += bf_hi(u4);
        px += bf_lo(u5);  py += bf_hi(u5);
        ax += bf_lo(u6);  ay += bf_hi(u6);
        px += bf_lo(u7);  py += bf_hi(u7);
    }
    if (j + 4 <= degc) {
        int2 q = *(const int2*)&bp[j];
        int s0 = q.x & 0xffff, s1 = (int)((unsigned)q.x >> 16);
        int s2 = q.y & 0xffff, s3 = (int)((unsigned)q.y >> 16);
        unsigned int u0 = xwb[(size_t)s0 * 64 + lane];
        unsigned int u1 = xwb[(size_t)s1 * 64 + lane];
        unsigned int u2 = xwb[(size_t)s2 * 64 + lane];
        unsigned int u3 = xwb[(size_t)s3 * 64 + lane];
        ax += bf_lo(u0);  ay += bf_hi(u0);
        px += bf_lo(u1);  py += bf_hi(u1);
        ax += bf_lo(u2);  ay += bf_hi(u2);
        px += bf_lo(u3);  py += bf_hi(u3);
        j += 4;
    }
    for (; j < degc; ++j) {
        int s = bp[j];
        unsigned int u = xwb[(size_t)s * 64 + lane];
        ax += bf_lo(u);
        ay += bf_hi(u);
    }
    ax += px;
    ay += py;
}

// ---- merged gemm1 + bucket build, roles INTERLEAVED in dispatch order ----

__global__ __launch_bounds__(256) void k_gemmbucket(const float* __restrict__ X,
                                                    const unsigned short* __restrict__ WT,
                                                    unsigned short* __restrict__ Yb, int n,
                                                    const int* __restrict__ src,
                                                    const int* __restrict__ dst,
                                                    int* __restrict__ cnt,
                                                    unsigned short* __restrict__ bkt,
                                                    int E, int EB8) {
    __shared__ unsigned short Ep[64 * LP];  // 17.4 KB epilogue tile (gemm role)
    int t = threadIdx.x;
    int b = blockIdx.x;
    int region = EB8 * 3;
    if (b < region && (b % 3) == 0) {  // ---- bucket role ----
        int bid = b / 3;
        int e0 = bid * 256 * EPT + t * EPT;
        if (e0 + EPT <= E) {
            int4 sa = *(const int4*)&src[e0];
            int4 sb = *(const int4*)&src[e0 + 4];
            int4 da = *(const int4*)&dst[e0];
            int4 db = *(const int4*)&dst[e0 + 4];
            int p;
            p = atomicAdd(&cnt[da.x], 1); if (p < BKT) bkt[(size_t)da.x * BKT + p] = (unsigned short)sa.x;
            p = atomicAdd(&cnt[da.y], 1); if (p < BKT) bkt[(size_t)da.y * BKT + p] = (unsigned short)sa.y;
            p = atomicAdd(&cnt[da.z], 1); if (p < BKT) bkt[(size_t)da.z * BKT + p] = (unsigned short)sa.z;
            p = atomicAdd(&cnt[da.w], 1); if (p < BKT) bkt[(size_t)da.w * BKT + p] = (unsigned short)sa.w;
            p = atomicAdd(&cnt[db.x], 1); if (p < BKT) bkt[(size_t)db.x * BKT + p] = (unsigned short)sb.x;
            p = atomicAdd(&cnt[db.y], 1); if (p < BKT) bkt[(size_t)db.y * BKT + p] = (unsigned short)sb.y;
            p = atomicAdd(&cnt[db.z], 1); if (p < BKT) bkt[(size_t)db.z * BKT + p] = (unsigned short)sb.z;
            p = atomicAdd(&cnt[db.w], 1); if (p < BKT) bkt[(size_t)db.w * BKT + p] = (unsigned short)sb.w;
        } else {
#pragma unroll
            for (int k = 0; k < EPT; ++k) {
                int e = e0 + k;
                if (e < E) {
                    int s = src[e], d = dst[e];
                    int pos = atomicAdd(&cnt[d], 1);
                    if (pos < BKT) bkt[(size_t)d * BKT + pos] = (unsigned short)s;
                }
            }
        }
        return;
    }
    // ---- gemm role ----
    int gb = (b < region) ? (b - (b + 2) / 3) : (b - EB8);
    int lane = t & 63, w = t >> 6;
    int m = lane & 15, quad = lane >> 4;
    int base = gb * 64 + w * 16;
    int row = min(base + m, n - 1);  // duplicate-row tail; stores guarded

    bf16x8 a[4];
#pragma unroll
    for (int kt = 0; kt < 4; ++kt) {
        const float* pa = &X[(size_t)row * 128 + kt * 32 + quad * 8];
        float4 v0 = *(const float4*)pa;
        float4 v1 = *(const float4*)(pa + 4);
        a[kt][0] = (short)f2bf_rn(v0.x); a[kt][1] = (short)f2bf_rn(v0.y);
        a[kt][2] = (short)f2bf_rn(v0.z); a[kt][3] = (short)f2bf_rn(v0.w);
        a[kt][4] = (short)f2bf_rn(v1.x); a[kt][5] = (short)f2bf_rn(v1.y);
        a[kt][6] = (short)f2bf_rn(v1.z); a[kt][7] = (short)f2bf_rn(v1.w);
    }

    f32x4 acc[8];
#pragma unroll
    for (int i = 0; i < 8; ++i) acc[i] = f32x4{0.f, 0.f, 0.f, 0.f};
#pragma unroll
    for (int kt = 0; kt < 4; ++kt) {
        int ko = kt * 32 + quad * 8;
#pragma unroll
        for (int ct = 0; ct < 8; ++ct) {
            bf16x8 bfrag = *(const bf16x8*)&WT[(ct * 16 + m) * 128 + ko];  // L1/L2-resident
            acc[ct] = __builtin_amdgcn_mfma_f32_16x16x32_bf16(a[kt], bfrag, acc[ct], 0, 0, 0);
        }
    }

    unsigned short* ep = &Ep[w * 16 * LP];
#pragma unroll
    for (int ct = 0; ct < 8; ++ct)
#pragma unroll
        for (int r = 0; r < 4; ++r)
            ep[(quad * 4 + r) * LP + ct * 16 + m] = f2bf_rn(acc[ct][r]);
    __syncthreads();
    int rr = lane & 15, cc = lane >> 4;
    int orow = base + rr;
    if (orow < n) {
#pragma unroll
        for (int i2 = 0; i2 < 4; ++i2)
            ((uint4*)&Yb[(size_t)orow * 128])[cc * 4 + i2] =
                *(const uint4*)&ep[rr * LP + (cc * 4 + i2) * 8];
    }
}

// ---- k_dinv: dinv[i] = rsqrt(deg+1) LUT (cnt final after gemmbucket) ----

__global__ __launch_bounds__(256) void k_dinv(const int* __restrict__ cnt,
                                              float* __restrict__ dinv, int N) {
    int i = blockIdx.x * 256 + threadIdx.x;
    if (i < N) dinv[i] = rsqrtf((float)cnt[i] + 1.0f);
}

// ---- fused agg(layer1)+gemm2: 64-node tile, 16 waves, 4 nodes/wave ----
// R1 skeleton (W2 in LDS, gather -> barrier -> MFMA) restored for occupancy:
// __launch_bounds__(1024,8) keeps VGPR<=64 so 2 blocks/CU (32 waves/CU) fit.
// 4 nodes/wave averages Poisson degree variance at the barrier (vs 1/wave).
// Per-edge weight from dinv LUT: chain is [load idx -> load row -> fma] with
// no cnt load / cvt / rsqrt. Epilogue prescales xw2 rows by dinv_row so k_agg
// stays pure-sum. LDS: 34 KB (W2) + 17.4 KB (At) + 256 B -> 2 blocks/CU.

__global__ __launch_bounds__(1024, 8) void k_aggemm(const unsigned int* __restrict__ xw1,
                                                    const int* __restrict__ cnt,
                                                    const unsigned short* __restrict__ bkt,
                                                    const float* __restrict__ dinv,
                                                    const float* __restrict__ bias,
                                                    const unsigned short* __restrict__ WT2,
                                                    unsigned short* __restrict__ xw2, int n) {
    __shared__ unsigned short Wl[128 * LP];  // 34 KB staged W2
    __shared__ unsigned short At[64 * LP];   // 17.4 KB: h tile, then output tile
    __shared__ float dsw[64];                // per-node dinv for epilogue prescale
    int t = threadIdx.x, lane = t & 63, w = t >> 6;
    int m = lane & 15, quad = lane >> 4;
    int base = blockIdx.x * 64;

    for (int idx = t; idx < 128 * 16; idx += 1024) {
        int r = idx >> 4, c8 = (idx & 15) << 3;
        *(uint4*)&Wl[r * LP + c8] = *(const uint4*)&WT2[r * 128 + c8];
    }
    float bx = bias[lane * 2], by = bias[lane * 2 + 1];

    // phase A: wave w gathers nodes base+4w .. base+4w+3
#pragma unroll
    for (int k = 0; k < 4; ++k) {
        int nd = w * 4 + k;
        int i = min(base + nd, n - 1);
        int degc = min(cnt[i], BKT);
        float di = dinv[i];
        unsigned int v0 = xw1[(size_t)i * 64 + lane];
        float ax = di * bf_lo(v0), ay = di * bf_hi(v0);
        gather_wsum(xw1, dinv, &bkt[(size_t)i * BKT], degc, lane, ax, ay);
        ax = fmaxf(fmaf(di, ax, bx), 0.0f);
        ay = fmaxf(fmaf(di, ay, by), 0.0f);
        ((unsigned int*)&At[nd * LP])[lane] =
            (unsigned)f2bf_rn(ax) | ((unsigned)f2bf_rn(ay) << 16);
        if (lane == 0) dsw[nd] = di;
    }
    __syncthreads();  // h tile + W2 staged

    // phase B: 64x128 gemm2. wave w: col-tile ct = w&7, row-tiles rb, rb+2
    int ct = w & 7, rb = w >> 3;
    f32x4 acc0 = f32x4{0.f, 0.f, 0.f, 0.f};
    f32x4 acc1 = f32x4{0.f, 0.f, 0.f, 0.f};
#pragma unroll
    for (int kt = 0; kt < 4; ++kt) {
        int ko = kt * 32 + quad * 8;
        bf16x8 bfrag = *(const bf16x8*)&Wl[(ct * 16 + m) * LP + ko];
        bf16x8 a0 = *(const bf16x8*)&At[(rb * 16 + m) * LP + ko];
        bf16x8 a1 = *(const bf16x8*)&At[((rb + 2) * 16 + m) * LP + ko];
        acc0 = __builtin_amdgcn_mfma_f32_16x16x32_bf16(a0, bfrag, acc0, 0, 0, 0);
        acc1 = __builtin_amdgcn_mfma_f32_16x16x32_bf16(a1, bfrag, acc1, 0, 0, 0);
    }
    __syncthreads();  // A reads done; overwrite At with PRESCALED output

#pragma unroll
    for (int r = 0; r < 4; ++r) {
        int r0 = rb * 16 + quad * 4 + r;
        int r1 = (rb + 2) * 16 + quad * 4 + r;
        At[r0 * LP + ct * 16 + m] = f2bf_rn(acc0[r] * dsw[r0]);
        At[r1 * LP + ct * 16 + m] = f2bf_rn(acc1[r] * dsw[r1]);
    }
    __syncthreads();

    int row = t >> 4, q = t & 15;  // 1024 threads: 64 rows x 16 uint4 slots
    int orow = base + row;
    if (orow < n)
        *(uint4*)&xw2[(size_t)orow * 128 + q * 8] = *(const uint4*)&At[row * LP + q * 8];
}

// ---- final aggregate (layer 2): prescaled sources -> pure row sum ----

__global__ __launch_bounds__(256) void k_agg(const unsigned int* __restrict__ xwb,
                                             const int* __restrict__ cnt,
                                             const unsigned short* __restrict__ bkt,
                                             const float* __restrict__ dinv,
                                             const float* __restrict__ bias,
                                             float* __restrict__ out, int n) {
    int lane = threadIdx.x & 63;
    int gw = (blockIdx.x * 256 + threadIdx.x) >> 6;
    int nw = (gridDim.x * 256) >> 6;
    float bx = bias[lane * 2], by = bias[lane * 2 + 1];
    for (int i = gw; i < n; i += nw) {
        int degc = min(cnt[i], BKT);
        float di = dinv[i];
        unsigned int v0 = xwb[(size_t)i * 64 + lane];
        float ax = bf_lo(v0), ay = bf_hi(v0);  // self term already prescaled
        gather_sum(xwb, &bkt[(size_t)i * BKT], degc, lane, ax, ay);
        ax = fmaxf(fmaf(di, ax, bx), 0.0f);
        ay = fmaxf(fmaf(di, ay, by), 0.0f);
        ((float2*)out)[(size_t)i * 64 + lane] = make_float2(ax, ay);
    }
}

// ---------------- launch ----------------

extern "C" void kernel_launch(void* const* d_in, const int* in_sizes, int n_in,
                              void* d_out, int out_size, void* d_ws, size_t ws_size,
                              hipStream_t stream) {
    const float* x  = (const float*)d_in[0];
    const int*   ei = (const int*)d_in[1];
    const float* W1 = (const float*)d_in[2];
    const float* b1 = (const float*)d_in[3];
    const float* W2 = (const float*)d_in[4];
    const float* b2 = (const float*)d_in[5];
    float* out = (float*)d_out;

    const int N = NNODES;
    const int E = in_sizes[1] / 2;  // 625000
    const int* src = ei;
    const int* dst = ei + E;

    char* p = (char*)d_ws;
    size_t off = 0;
    auto take = [&](size_t bytes) -> void* {
        void* r = p + off;
        off = (off + bytes + 255) & ~(size_t)255;
        return r;
    };
    int* cnt = (int*)take((size_t)N * 4);
    unsigned short* bkt = (unsigned short*)take((size_t)N * BKT * 2);  // 6.4 MB u16
    unsigned short* w1t = (unsigned short*)take(128 * 128 * 2);
    unsigned short* w2t = (unsigned short*)take(128 * 128 * 2);
    unsigned short* xw1 = (unsigned short*)take((size_t)N * 128 * 2);  // bf16 x@W1
    unsigned short* xw2 = (unsigned short*)take((size_t)N * 128 * 2);  // bf16 dinv*(h@W2)
    float* dinv = (float*)take((size_t)N * 4);                         // rsqrt(deg+1) LUT

    const int NB = (N + 255) / 256;              // cnt-zero / dinv blocks
    const int EB8 = (E + 256 * EPT - 1) / (256 * EPT);  // 306 bucket blocks
    const int GB = (N + 63) / 64;                // 782 gemm/aggemm blocks

    // 1: W transposes + cnt zero
    k_wt<<<2 + NB, 256, 0, stream>>>(W1, W2, w1t, w2t, cnt, N);
    // 2: interleaved bucket build + gemm1 (disjoint inputs, co-resident roles)
    k_gemmbucket<<<EB8 + GB, 256, 0, stream>>>(x, w1t, xw1, N, src, dst, cnt, bkt, E, EB8);
    // 3: dinv LUT (cnt final)
    k_dinv<<<NB, 256, 0, stream>>>(cnt, dinv, N);
    // 4: fused agg(layer1)+bias+relu+gemm2 (+free dinv prescale of xw2)
    k_aggemm<<<GB, 1024, 0, stream>>>((const unsigned int*)xw1, cnt, bkt, dinv,
                                      b1, w2t, xw2, N);
    // 5: final aggregate + bias + relu (fp32 out)
    k_agg<<<AGG_BLOCKS, 256, 0, stream>>>((const unsigned int*)xw2, cnt, bkt, dinv,
                                          b2, out, N);
}

// Round 5
// 191.629 us; speedup vs baseline: 1.2685x; 1.0057x over previous
//
#include <hip/hip_runtime.h>
#include <hip/hip_bf16.h>

#define NNODES 50000
#define BKT 64   // bucket capacity; deg ~ Poisson(12.5), P(>64) ~ 1e-38 (clamped)
#define LP 136   // padded bf16 LDS row (272 B = 16*17): b128-aligned, mild bank stagger
#define EPT 8    // edges per thread in bucket role (8 independent atomic chains)
#define CPAD 16  // cnt padding: 1 counter per 64B line -> no same-line atomic serialization
#define AGG_BLOCKS 2048

typedef short bf16x8 __attribute__((ext_vector_type(8)));
typedef float f32x4 __attribute__((ext_vector_type(4)));

__device__ __forceinline__ unsigned short f2bf_rn(float f) {
    unsigned int u = __float_as_uint(f);
    return (unsigned short)((u + 0x7fffu + ((u >> 16) & 1u)) >> 16);
}
__device__ __forceinline__ float bf_lo(unsigned int u) { return __uint_as_float(u << 16); }
__device__ __forceinline__ float bf_hi(unsigned int u) { return __uint_as_float(u & 0xffff0000u); }

// ---- k_wt: blocks 0,1 transpose W->bf16 WT[c][k]; blocks 2+ zero padded cntp ----

__global__ __launch_bounds__(256) void k_wt(const float* __restrict__ W1,
                                            const float* __restrict__ W2,
                                            unsigned short* __restrict__ WT1,
                                            unsigned short* __restrict__ WT2,
                                            int* __restrict__ cntp, int N) {
    __shared__ float tile[128 * 129];
    int b = blockIdx.x, t = threadIdx.x;
    if (b < 2) {
        const float* W = b ? W2 : W1;
        unsigned short* WT = b ? WT2 : WT1;
        for (int idx = t; idx < 128 * 128; idx += 256)
            tile[(idx >> 7) * 129 + (idx & 127)] = W[idx];
        __syncthreads();
        for (int idx = t; idx < 128 * 128; idx += 256) {
            int c = idx >> 7, k = idx & 127;
            WT[c * 128 + k] = f2bf_rn(tile[k * 129 + c]);
        }
    } else {
        int i = (b - 2) * 256 + t;
        if (i < N) cntp[i * CPAD] = 0;
    }
}

// ---- weighted gather (layer 1): weight = dinv[s] from f32 LUT ----

__device__ __forceinline__ void gather_wsum(const unsigned int* __restrict__ xwb,
                                            const float* __restrict__ dinv,
                                            const unsigned short* __restrict__ bp,
                                            int degc, int lane,
                                            float& ax, float& ay) {
    float px = 0.f, py = 0.f;
    int j = 0;
    for (; j + 8 <= degc; j += 8) {
        int4 q = *(const int4*)&bp[j];  // 8 x u16 ids
        int s0 = q.x & 0xffff, s1 = (int)((unsigned)q.x >> 16);
        int s2 = q.y & 0xffff, s3 = (int)((unsigned)q.y >> 16);
        int s4 = q.z & 0xffff, s5 = (int)((unsigned)q.z >> 16);
        int s6 = q.w & 0xffff, s7 = (int)((unsigned)q.w >> 16);
        unsigned int u0 = xwb[(size_t)s0 * 64 + lane];
        unsigned int u1 = xwb[(size_t)s1 * 64 + lane];
        unsigned int u2 = xwb[(size_t)s2 * 64 + lane];
        unsigned int u3 = xwb[(size_t)s3 * 64 + lane];
        unsigned int u4 = xwb[(size_t)s4 * 64 + lane];
        unsigned int u5 = xwb[(size_t)s5 * 64 + lane];
        unsigned int u6 = xwb[(size_t)s6 * 64 + lane];
        unsigned int u7 = xwb[(size_t)s7 * 64 + lane];
        float w0 = dinv[s0], w1 = dinv[s1], w2 = dinv[s2], w3 = dinv[s3];
        float w4 = dinv[s4], w5 = dinv[s5], w6 = dinv[s6], w7 = dinv[s7];
        ax = fmaf(bf_lo(u0), w0, ax);  ay = fmaf(bf_hi(u0), w0, ay);
        px = fmaf(bf_lo(u1), w1, px);  py = fmaf(bf_hi(u1), w1, py);
        ax = fmaf(bf_lo(u2), w2, ax);  ay = fmaf(bf_hi(u2), w2, ay);
        px = fmaf(bf_lo(u3), w3, px);  py = fmaf(bf_hi(u3), w3, py);
        ax = fmaf(bf_lo(u4), w4, ax);  ay = fmaf(bf_hi(u4), w4, ay);
        px = fmaf(bf_lo(u5), w5, px);  py = fmaf(bf_hi(u5), w5, py);
        ax = fmaf(bf_lo(u6), w6, ax);  ay = fmaf(bf_hi(u6), w6, ay);
        px = fmaf(bf_lo(u7), w7, px);  py = fmaf(bf_hi(u7), w7, py);
    }
    if (j + 4 <= degc) {
        int2 q = *(const int2*)&bp[j];
        int s0 = q.x & 0xffff, s1 = (int)((unsigned)q.x >> 16);
        int s2 = q.y & 0xffff, s3 = (int)((unsigned)q.y >> 16);
        unsigned int u0 = xwb[(size_t)s0 * 64 + lane];
        unsigned int u1 = xwb[(size_t)s1 * 64 + lane];
        unsigned int u2 = xwb[(size_t)s2 * 64 + lane];
        unsigned int u3 = xwb[(size_t)s3 * 64 + lane];
        float w0 = dinv[s0], w1 = dinv[s1], w2 = dinv[s2], w3 = dinv[s3];
        ax = fmaf(bf_lo(u0), w0, ax);  ay = fmaf(bf_hi(u0), w0, ay);
        px = fmaf(bf_lo(u1), w1, px);  py = fmaf(bf_hi(u1), w1, py);
        ax = fmaf(bf_lo(u2), w2, ax);  ay = fmaf(bf_hi(u2), w2, ay);
        px = fmaf(bf_lo(u3), w3, px);  py = fmaf(bf_hi(u3), w3, py);
        j += 4;
    }
    for (; j < degc; ++j) {
        int s = bp[j];
        float wv = dinv[s];
        unsigned int u = xwb[(size_t)s * 64 + lane];
        ax = fmaf(bf_lo(u), wv, ax);
        ay = fmaf(bf_hi(u), wv, ay);
    }
    ax += px;
    ay += py;
}

// ---- pure-sum gather (layer 2; sources PRESCALED by dinv at xw2 write) ----

__device__ __forceinline__ void gather_sum(const unsigned int* __restrict__ xwb,
                                           const unsigned short* __restrict__ bp,
                                           int degc, int lane,
                                           float& ax, float& ay) {
    float px = 0.f, py = 0.f;
    int j = 0;
    for (; j + 8 <= degc; j += 8) {
        int4 q = *(const int4*)&bp[j];
        int s0 = q.x & 0xffff, s1 = (int)((unsigned)q.x >> 16);
        int s2 = q.y & 0xffff, s3 = (int)((unsigned)q.y >> 16);
        int s4 = q.z & 0xffff, s5 = (int)((unsigned)q.z >> 16);
        int s6 = q.w & 0xffff, s7 = (int)((unsigned)q.w >> 16);
        unsigned int u0 = xwb[(size_t)s0 * 64 + lane];
        unsigned int u1 = xwb[(size_t)s1 * 64 + lane];
        unsigned int u2 = xwb[(size_t)s2 * 64 + lane];
        unsigned int u3 = xwb[(size_t)s3 * 64 + lane];
        unsigned int u4 = xwb[(size_t)s4 * 64 + lane];
        unsigned int u5 = xwb[(size_t)s5 * 64 + lane];
        unsigned int u6 = xwb[(size_t)s6 * 64 + lane];
        unsigned int u7 = xwb[(size_t)s7 * 64 + lane];
        ax += bf_lo(u0);  ay += bf_hi(u0);
        px += bf_lo(u1);  py += bf_hi(u1);
        ax += bf_lo(u2);  ay += bf_hi(u2);
        px += bf_lo(u3);  py += bf_hi(u3);
        ax += bf_lo(u4);  ay += bf_hi(u4);
        px += bf_lo(u5);  py += bf_hi(u5);
        ax += bf_lo(u6);  ay += bf_hi(u6);
        px += bf_lo(u7);  py += bf_hi(u7);
    }
    if (j + 4 <= degc) {
        int2 q = *(const int2*)&bp[j];
        int s0 = q.x & 0xffff, s1 = (int)((unsigned)q.x >> 16);
        int s2 = q.y & 0xffff, s3 = (int)((unsigned)q.y >> 16);
        unsigned int u0 = xwb[(size_t)s0 * 64 + lane];
        unsigned int u1 = xwb[(size_t)s1 * 64 + lane];
        unsigned int u2 = xwb[(size_t)s2 * 64 + lane];
        unsigned int u3 = xwb[(size_t)s3 * 64 + lane];
        ax += bf_lo(u0);  ay += bf_hi(u0);
        px += bf_lo(u1);  py += bf_hi(u1);
        ax += bf_lo(u2);  ay += bf_hi(u2);
        px += bf_lo(u3);  py += bf_hi(u3);
        j += 4;
    }
    for (; j < degc; ++j) {
        int s = bp[j];
        unsigned int u = xwb[(size_t)s * 64 + lane];
        ax += bf_lo(u);
        ay += bf_hi(u);
    }
    ax += px;
    ay += py;
}

// ---- merged gemm1 + bucket build, roles INTERLEAVED in dispatch order ----
// Bucket atomics hit cntp[d*CPAD]: one counter per 64B line, so same-line
// serialization at the coherence point is eliminated (single-variable test).

__global__ __launch_bounds__(256) void k_gemmbucket(const float* __restrict__ X,
                                                    const unsigned short* __restrict__ WT,
                                                    unsigned short* __restrict__ Yb, int n,
                                                    const int* __restrict__ src,
                                                    const int* __restrict__ dst,
                                                    int* __restrict__ cntp,
                                                    unsigned short* __restrict__ bkt,
                                                    int E, int EB8) {
    __shared__ unsigned short Ep[64 * LP];  // 17.4 KB epilogue tile (gemm role)
    int t = threadIdx.x;
    int b = blockIdx.x;
    int region = EB8 * 3;
    if (b < region && (b % 3) == 0) {  // ---- bucket role ----
        int bid = b / 3;
        int e0 = bid * 256 * EPT + t * EPT;
        if (e0 + EPT <= E) {
            int4 sa = *(const int4*)&src[e0];
            int4 sb = *(const int4*)&src[e0 + 4];
            int4 da = *(const int4*)&dst[e0];
            int4 db = *(const int4*)&dst[e0 + 4];
            int p;
            p = atomicAdd(&cntp[da.x * CPAD], 1); if (p < BKT) bkt[(size_t)da.x * BKT + p] = (unsigned short)sa.x;
            p = atomicAdd(&cntp[da.y * CPAD], 1); if (p < BKT) bkt[(size_t)da.y * BKT + p] = (unsigned short)sa.y;
            p = atomicAdd(&cntp[da.z * CPAD], 1); if (p < BKT) bkt[(size_t)da.z * BKT + p] = (unsigned short)sa.z;
            p = atomicAdd(&cntp[da.w * CPAD], 1); if (p < BKT) bkt[(size_t)da.w * BKT + p] = (unsigned short)sa.w;
            p = atomicAdd(&cntp[db.x * CPAD], 1); if (p < BKT) bkt[(size_t)db.x * BKT + p] = (unsigned short)sb.x;
            p = atomicAdd(&cntp[db.y * CPAD], 1); if (p < BKT) bkt[(size_t)db.y * BKT + p] = (unsigned short)sb.y;
            p = atomicAdd(&cntp[db.z * CPAD], 1); if (p < BKT) bkt[(size_t)db.z * BKT + p] = (unsigned short)sb.z;
            p = atomicAdd(&cntp[db.w * CPAD], 1); if (p < BKT) bkt[(size_t)db.w * BKT + p] = (unsigned short)sb.w;
        } else {
#pragma unroll
            for (int k = 0; k < EPT; ++k) {
                int e = e0 + k;
                if (e < E) {
                    int s = src[e], d = dst[e];
                    int pos = atomicAdd(&cntp[d * CPAD], 1);
                    if (pos < BKT) bkt[(size_t)d * BKT + pos] = (unsigned short)s;
                }
            }
        }
        return;
    }
    // ---- gemm role ----
    int gb = (b < region) ? (b - (b + 2) / 3) : (b - EB8);
    int lane = t & 63, w = t >> 6;
    int m = lane & 15, quad = lane >> 4;
    int base = gb * 64 + w * 16;
    int row = min(base + m, n - 1);  // duplicate-row tail; stores guarded

    bf16x8 a[4];
#pragma unroll
    for (int kt = 0; kt < 4; ++kt) {
        const float* pa = &X[(size_t)row * 128 + kt * 32 + quad * 8];
        float4 v0 = *(const float4*)pa;
        float4 v1 = *(const float4*)(pa + 4);
        a[kt][0] = (short)f2bf_rn(v0.x); a[kt][1] = (short)f2bf_rn(v0.y);
        a[kt][2] = (short)f2bf_rn(v0.z); a[kt][3] = (short)f2bf_rn(v0.w);
        a[kt][4] = (short)f2bf_rn(v1.x); a[kt][5] = (short)f2bf_rn(v1.y);
        a[kt][6] = (short)f2bf_rn(v1.z); a[kt][7] = (short)f2bf_rn(v1.w);
    }

    f32x4 acc[8];
#pragma unroll
    for (int i = 0; i < 8; ++i) acc[i] = f32x4{0.f, 0.f, 0.f, 0.f};
#pragma unroll
    for (int kt = 0; kt < 4; ++kt) {
        int ko = kt * 32 + quad * 8;
#pragma unroll
        for (int ct = 0; ct < 8; ++ct) {
            bf16x8 bfrag = *(const bf16x8*)&WT[(ct * 16 + m) * 128 + ko];  // L1/L2-resident
            acc[ct] = __builtin_amdgcn_mfma_f32_16x16x32_bf16(a[kt], bfrag, acc[ct], 0, 0, 0);
        }
    }

    unsigned short* ep = &Ep[w * 16 * LP];
#pragma unroll
    for (int ct = 0; ct < 8; ++ct)
#pragma unroll
        for (int r = 0; r < 4; ++r)
            ep[(quad * 4 + r) * LP + ct * 16 + m] = f2bf_rn(acc[ct][r]);
    __syncthreads();
    int rr = lane & 15, cc = lane >> 4;
    int orow = base + rr;
    if (orow < n) {
#pragma unroll
        for (int i2 = 0; i2 < 4; ++i2)
            ((uint4*)&Yb[(size_t)orow * 128])[cc * 4 + i2] =
                *(const uint4*)&ep[rr * LP + (cc * 4 + i2) * 8];
    }
}

// ---- k_dinv: compact cntp -> cnt, and dinv[i] = rsqrt(deg+1) LUT ----

__global__ __launch_bounds__(256) void k_dinv(const int* __restrict__ cntp,
                                              int* __restrict__ cnt,
                                              float* __restrict__ dinv, int N) {
    int i = blockIdx.x * 256 + threadIdx.x;
    if (i < N) {
        int c = cntp[i * CPAD];
        cnt[i] = c;
        dinv[i] = rsqrtf((float)c + 1.0f);
    }
}

// ---- fused agg(layer1)+gemm2: 64-node tile, 16 waves, 4 nodes/wave ----

__global__ __launch_bounds__(1024, 8) void k_aggemm(const unsigned int* __restrict__ xw1,
                                                    const int* __restrict__ cnt,
                                                    const unsigned short* __restrict__ bkt,
                                                    const float* __restrict__ dinv,
                                                    const float* __restrict__ bias,
                                                    const unsigned short* __restrict__ WT2,
                                                    unsigned short* __restrict__ xw2, int n) {
    __shared__ unsigned short Wl[128 * LP];  // 34 KB staged W2
    __shared__ unsigned short At[64 * LP];   // 17.4 KB: h tile, then output tile
    __shared__ float dsw[64];                // per-node dinv for epilogue prescale
    int t = threadIdx.x, lane = t & 63, w = t >> 6;
    int m = lane & 15, quad = lane >> 4;
    int base = blockIdx.x * 64;

    for (int idx = t; idx < 128 * 16; idx += 1024) {
        int r = idx >> 4, c8 = (idx & 15) << 3;
        *(uint4*)&Wl[r * LP + c8] = *(const uint4*)&WT2[r * 128 + c8];
    }
    float bx = bias[lane * 2], by = bias[lane * 2 + 1];

    // phase A: wave w gathers nodes base+4w .. base+4w+3
#pragma unroll
    for (int k = 0; k < 4; ++k) {
        int nd = w * 4 + k;
        int i = min(base + nd, n - 1);
        int degc = min(cnt[i], BKT);
        float di = dinv[i];
        unsigned int v0 = xw1[(size_t)i * 64 + lane];
        float ax = di * bf_lo(v0), ay = di * bf_hi(v0);
        gather_wsum(xw1, dinv, &bkt[(size_t)i * BKT], degc, lane, ax, ay);
        ax = fmaxf(fmaf(di, ax, bx), 0.0f);
        ay = fmaxf(fmaf(di, ay, by), 0.0f);
        ((unsigned int*)&At[nd * LP])[lane] =
            (unsigned)f2bf_rn(ax) | ((unsigned)f2bf_rn(ay) << 16);
        if (lane == 0) dsw[nd] = di;
    }
    __syncthreads();  // h tile + W2 staged

    // phase B: 64x128 gemm2. wave w: col-tile ct = w&7, row-tiles rb, rb+2
    int ct = w & 7, rb = w >> 3;
    f32x4 acc0 = f32x4{0.f, 0.f, 0.f, 0.f};
    f32x4 acc1 = f32x4{0.f, 0.f, 0.f, 0.f};
#pragma unroll
    for (int kt = 0; kt < 4; ++kt) {
        int ko = kt * 32 + quad * 8;
        bf16x8 bfrag = *(const bf16x8*)&Wl[(ct * 16 + m) * LP + ko];
        bf16x8 a0 = *(const bf16x8*)&At[(rb * 16 + m) * LP + ko];
        bf16x8 a1 = *(const bf16x8*)&At[((rb + 2) * 16 + m) * LP + ko];
        acc0 = __builtin_amdgcn_mfma_f32_16x16x32_bf16(a0, bfrag, acc0, 0, 0, 0);
        acc1 = __builtin_amdgcn_mfma_f32_16x16x32_bf16(a1, bfrag, acc1, 0, 0, 0);
    }
    __syncthreads();  // A reads done; overwrite At with PRESCALED output

#pragma unroll
    for (int r = 0; r < 4; ++r) {
        int r0 = rb * 16 + quad * 4 + r;
        int r1 = (rb + 2) * 16 + quad * 4 + r;
        At[r0 * LP + ct * 16 + m] = f2bf_rn(acc0[r] * dsw[r0]);
        At[r1 * LP + ct * 16 + m] = f2bf_rn(acc1[r] * dsw[r1]);
    }
    __syncthreads();

    int row = t >> 4, q = t & 15;  // 1024 threads: 64 rows x 16 uint4 slots
    int orow = base + row;
    if (orow < n)
        *(uint4*)&xw2[(size_t)orow * 128 + q * 8] = *(const uint4*)&At[row * LP + q * 8];
}

// ---- final aggregate (layer 2): prescaled sources -> pure row sum ----

__global__ __launch_bounds__(256) void k_agg(const unsigned int* __restrict__ xwb,
                                             const int* __restrict__ cnt,
                                             const unsigned short* __restrict__ bkt,
                                             const float* __restrict__ dinv,
                                             const float* __restrict__ bias,
                                             float* __restrict__ out, int n) {
    int lane = threadIdx.x & 63;
    int gw = (blockIdx.x * 256 + threadIdx.x) >> 6;
    int nw = (gridDim.x * 256) >> 6;
    float bx = bias[lane * 2], by = bias[lane * 2 + 1];
    for (int i = gw; i < n; i += nw) {
        int degc = min(cnt[i], BKT);
        float di = dinv[i];
        unsigned int v0 = xwb[(size_t)i * 64 + lane];
        float ax = bf_lo(v0), ay = bf_hi(v0);  // self term already prescaled
        gather_sum(xwb, &bkt[(size_t)i * BKT], degc, lane, ax, ay);
        ax = fmaxf(fmaf(di, ax, bx), 0.0f);
        ay = fmaxf(fmaf(di, ay, by), 0.0f);
        ((float2*)out)[(size_t)i * 64 + lane] = make_float2(ax, ay);
    }
}

// ---------------- launch ----------------

extern "C" void kernel_launch(void* const* d_in, const int* in_sizes, int n_in,
                              void* d_out, int out_size, void* d_ws, size_t ws_size,
                              hipStream_t stream) {
    const float* x  = (const float*)d_in[0];
    const int*   ei = (const int*)d_in[1];
    const float* W1 = (const float*)d_in[2];
    const float* b1 = (const float*)d_in[3];
    const float* W2 = (const float*)d_in[4];
    const float* b2 = (const float*)d_in[5];
    float* out = (float*)d_out;

    const int N = NNODES;
    const int E = in_sizes[1] / 2;  // 625000
    const int* src = ei;
    const int* dst = ei + E;

    char* p = (char*)d_ws;
    size_t off = 0;
    auto take = [&](size_t bytes) -> void* {
        void* r = p + off;
        off = (off + bytes + 255) & ~(size_t)255;
        return r;
    };
    int* cnt = (int*)take((size_t)N * 4);                      // compact (downstream reads)
    int* cntp = (int*)take((size_t)N * CPAD * 4);              // 3.2 MB padded atomic target
    unsigned short* bkt = (unsigned short*)take((size_t)N * BKT * 2);  // 6.4 MB u16
    unsigned short* w1t = (unsigned short*)take(128 * 128 * 2);
    unsigned short* w2t = (unsigned short*)take(128 * 128 * 2);
    unsigned short* xw1 = (unsigned short*)take((size_t)N * 128 * 2);  // bf16 x@W1
    unsigned short* xw2 = (unsigned short*)take((size_t)N * 128 * 2);  // bf16 dinv*(h@W2)
    float* dinv = (float*)take((size_t)N * 4);                         // rsqrt(deg+1) LUT

    const int NB = (N + 255) / 256;              // cntp-zero / dinv blocks
    const int EB8 = (E + 256 * EPT - 1) / (256 * EPT);  // 306 bucket blocks
    const int GB = (N + 63) / 64;                // 782 gemm/aggemm blocks

    // 1: W transposes + cntp zero
    k_wt<<<2 + NB, 256, 0, stream>>>(W1, W2, w1t, w2t, cntp, N);
    // 2: interleaved bucket build + gemm1 (line-padded atomics)
    k_gemmbucket<<<EB8 + GB, 256, 0, stream>>>(x, w1t, xw1, N, src, dst, cntp, bkt, E, EB8);
    // 3: compact cnt + dinv LUT
    k_dinv<<<NB, 256, 0, stream>>>(cntp, cnt, dinv, N);
    // 4: fused agg(layer1)+bias+relu+gemm2 (+free dinv prescale of xw2)
    k_aggemm<<<GB, 1024, 0, stream>>>((const unsigned int*)xw1, cnt, bkt, dinv,
                                      b1, w2t, xw2, N);
    // 5: final aggregate + bias + relu (fp32 out)
    k_agg<<<AGG_BLOCKS, 256, 0, stream>>>((const unsigned int*)xw2, cnt, bkt, dinv,
                                          b2, out, N);
}